// Round 1
// baseline (2939.605 us; speedup 1.0000x reference)
//
#include <hip/hip_runtime.h>
#include <math.h>

// Swin block: B=8 H=W=128 C=256 NH=8 HD=32 WS=8 SS=4, N=64 tokens/window,
// 2048 windows total, 131072 tokens total.

#define NWIN_TOTAL 2048
#define TOK_TOTAL  131072
#define SCALE_Q    0.17677669529663687f  // 32^-0.5

__device__ __forceinline__ int regid3(int h) { return h < 120 ? 0 : (h < 124 ? 1 : 2); }
__device__ __forceinline__ float gelu_f(float v) {
  return 0.5f * v * (1.0f + erff(v * 0.7071067811865475f));
}

// (window g, token n) -> flat token index in image space (shift applied).
// rolled[hs] = orig[(hs+4)%128]; window (wr,wc), in-window (i,j).
__device__ __forceinline__ int win_tok_to_t(int g, int n) {
  int b = g >> 8, wi = g & 255;
  int wr = wi >> 4, wc = wi & 15;
  int hs = wr * 8 + (n >> 3), ws2 = wc * 8 + (n & 7);
  int h = (hs + 4) & 127, w = (ws2 + 4) & 127;
  return (b << 14) + (h << 7) + w;
}

// ---------------- LN1 (gather into window order) ----------------
// one wave (64 lanes) per token; 256 channels = 64 lanes x float4
__global__ __launch_bounds__(256)
void ln1_kernel(const float* __restrict__ x, const float* __restrict__ g1,
                const float* __restrict__ b1, float* __restrict__ outw, int g0)
{
  int gid  = blockIdx.x * 4 + (threadIdx.x >> 6);  // token within chunk
  int lane = threadIdx.x & 63;
  int g = g0 + (gid >> 6);
  int t = win_tok_to_t(g, gid & 63);
  float4 v = ((const float4*)x)[(size_t)t * 64 + lane];
  float s = v.x + v.y + v.z + v.w;
  float q = v.x * v.x + v.y * v.y + v.z * v.z + v.w * v.w;
#pragma unroll
  for (int m = 1; m < 64; m <<= 1) { s += __shfl_xor(s, m, 64); q += __shfl_xor(q, m, 64); }
  float mean = s * 0.00390625f;
  float var  = q * 0.00390625f - mean * mean;
  float rstd = rsqrtf(var + 1e-5f);
  float4 gg = ((const float4*)g1)[lane];
  float4 bb = ((const float4*)b1)[lane];
  float4 o;
  o.x = (v.x - mean) * rstd * gg.x + bb.x;
  o.y = (v.y - mean) * rstd * gg.y + bb.y;
  o.z = (v.z - mean) * rstd * gg.z + bb.z;
  o.w = (v.w - mean) * rstd * gg.w + bb.w;
  ((float4*)outw)[(size_t)gid * 64 + lane] = o;
}

// ---------------- generic fp32 GEMM, 128x128x16 tile ----------------
// MODE 0: plain + bias -> o0[row*N+col]                 (proj)
// MODE 1: + bias, q-scale, scatter to q/k/v head-major  (qkv)
// MODE 2: A = LN2-on-the-fly from xsrc/stats, +bias, GELU -> o0 (fc1)
// MODE 3: + bias + resid -> o0 (fc2, N=256)
struct GArgs {
  const float* A; const float* Bw; const float* bias;
  float* o0; float* o1; float* o2;
  int M, N, K;
  const float* xsrc; const float2* stats;
  const float* gamma; const float* beta;
  const float* resid;
};

template<int MODE>
__global__ __launch_bounds__(256)
void gemm_kernel(GArgs a)
{
  __shared__ float As[16][128];
  __shared__ float Bs[16][128];
  const int tid = threadIdx.x;
  const int tx = tid & 15, ty = tid >> 4;
  const int rowBase = blockIdx.y * 128;
  const int colBase = blockIdx.x * 128;
  // staging: 512 float4 slots each for A(128x16) and B(16x128); 2 per thread
  const int sA   = tid * 2;
  const int arow = sA >> 2;
  const int ak0  = (sA & 3) * 4;          // 0 or 8 -> loads 8 contiguous k
  const int sB   = tid * 2;
  const int brow = sB >> 5;
  const int bc0  = (sB & 31) * 4;         // 8 contiguous cols

  float acc[8][8];
#pragma unroll
  for (int i = 0; i < 8; ++i)
#pragma unroll
    for (int j = 0; j < 8; ++j) acc[i][j] = 0.f;

  const int nkt = a.K >> 4;
  for (int kt = 0; kt < nkt; ++kt) {
    const int kk = kt * 16;
    // ---- stage A (transposed into As[k][m]) ----
    float v8[8];
    if (MODE == 2) {
      float2 st = a.stats[rowBase + arow];
      const float* xr = a.xsrc + (size_t)(rowBase + arow) * 256 + kk + ak0;
      float4 x0 = *(const float4*)xr;
      float4 x1 = *(const float4*)(xr + 4);
      float4 gm0 = *(const float4*)(a.gamma + kk + ak0);
      float4 gm1 = *(const float4*)(a.gamma + kk + ak0 + 4);
      float4 bt0 = *(const float4*)(a.beta + kk + ak0);
      float4 bt1 = *(const float4*)(a.beta + kk + ak0 + 4);
      v8[0] = (x0.x - st.x) * st.y * gm0.x + bt0.x;
      v8[1] = (x0.y - st.x) * st.y * gm0.y + bt0.y;
      v8[2] = (x0.z - st.x) * st.y * gm0.z + bt0.z;
      v8[3] = (x0.w - st.x) * st.y * gm0.w + bt0.w;
      v8[4] = (x1.x - st.x) * st.y * gm1.x + bt1.x;
      v8[5] = (x1.y - st.x) * st.y * gm1.y + bt1.y;
      v8[6] = (x1.z - st.x) * st.y * gm1.z + bt1.z;
      v8[7] = (x1.w - st.x) * st.y * gm1.w + bt1.w;
    } else {
      const float* ar = a.A + (size_t)(rowBase + arow) * a.K + kk + ak0;
      float4 x0 = *(const float4*)ar;
      float4 x1 = *(const float4*)(ar + 4);
      v8[0] = x0.x; v8[1] = x0.y; v8[2] = x0.z; v8[3] = x0.w;
      v8[4] = x1.x; v8[5] = x1.y; v8[6] = x1.z; v8[7] = x1.w;
    }
#pragma unroll
    for (int i = 0; i < 8; ++i) As[ak0 + i][arow] = v8[i];
    // ---- stage B ----
    {
      const float* br = a.Bw + (size_t)(kk + brow) * a.N + colBase + bc0;
      float4 b0 = *(const float4*)br;
      float4 b1 = *(const float4*)(br + 4);
      *(float4*)&Bs[brow][bc0]     = b0;
      *(float4*)&Bs[brow][bc0 + 4] = b1;
    }
    __syncthreads();
#pragma unroll
    for (int k = 0; k < 16; ++k) {
      float4 a0 = *(const float4*)&As[k][ty * 8];
      float4 a1 = *(const float4*)&As[k][ty * 8 + 4];
      float4 b0 = *(const float4*)&Bs[k][tx * 8];
      float4 b1 = *(const float4*)&Bs[k][tx * 8 + 4];
      float ar8[8] = {a0.x, a0.y, a0.z, a0.w, a1.x, a1.y, a1.z, a1.w};
      float br8[8] = {b0.x, b0.y, b0.z, b0.w, b1.x, b1.y, b1.z, b1.w};
#pragma unroll
      for (int i = 0; i < 8; ++i)
#pragma unroll
        for (int j = 0; j < 8; ++j) acc[i][j] += ar8[i] * br8[j];
    }
    __syncthreads();
  }

  // ---- epilogue ----
  const int col0 = colBase + tx * 8;
  float4 bias0 = *(const float4*)&a.bias[col0];
  float4 bias1 = *(const float4*)&a.bias[col0 + 4];
  float bias8[8] = {bias0.x, bias0.y, bias0.z, bias0.w, bias1.x, bias1.y, bias1.z, bias1.w};
#pragma unroll
  for (int r = 0; r < 8; ++r) {
    int row = rowBase + ty * 8 + r;
    float v[8];
#pragma unroll
    for (int j = 0; j < 8; ++j) v[j] = acc[r][j] + bias8[j];
    if (MODE == 0) {
      float4* dst = (float4*)(a.o0 + (size_t)row * a.N + col0);
      dst[0] = make_float4(v[0], v[1], v[2], v[3]);
      dst[1] = make_float4(v[4], v[5], v[6], v[7]);
    } else if (MODE == 1) {
      int gw = row >> 6, n = row & 63;
#pragma unroll
      for (int gq = 0; gq < 2; ++gq) {
        int c = col0 + gq * 4;
        int s = c >> 8, head = (c >> 5) & 7, hd = c & 31;
        float* dstb = (s == 0) ? a.o0 : ((s == 1) ? a.o1 : a.o2);
        float m0 = v[gq*4+0], m1 = v[gq*4+1], m2 = v[gq*4+2], m3 = v[gq*4+3];
        if (s == 0) { m0 *= SCALE_Q; m1 *= SCALE_Q; m2 *= SCALE_Q; m3 *= SCALE_Q; }
        *(float4*)&dstb[(((size_t)(gw << 3) + head) << 11) + (n << 5) + hd] =
            make_float4(m0, m1, m2, m3);
      }
    } else if (MODE == 2) {
      float4* dst = (float4*)(a.o0 + (size_t)row * a.N + col0);
      dst[0] = make_float4(gelu_f(v[0]), gelu_f(v[1]), gelu_f(v[2]), gelu_f(v[3]));
      dst[1] = make_float4(gelu_f(v[4]), gelu_f(v[5]), gelu_f(v[6]), gelu_f(v[7]));
    } else {  // MODE 3
      const float4* rs = (const float4*)(a.resid + (size_t)row * 256 + col0);
      float4 r0 = rs[0], r1 = rs[1];
      float4* dst = (float4*)(a.o0 + (size_t)row * 256 + col0);
      dst[0] = make_float4(v[0] + r0.x, v[1] + r0.y, v[2] + r0.z, v[3] + r0.w);
      dst[1] = make_float4(v[4] + r1.x, v[5] + r1.y, v[6] + r1.z, v[7] + r1.w);
    }
  }
}

// ---------------- windowed attention: one wave per (window, head) ----------------
__global__ __launch_bounds__(64)
void attn_kernel(const float* __restrict__ qb, const float* __restrict__ kb,
                 const float* __restrict__ vb, const float* __restrict__ rpb,
                 float* __restrict__ ao, int g0)
{
  __shared__ float kls[64 * 32];
  __shared__ float vls[64 * 32];
  int bw = blockIdx.x >> 3;   // window within chunk
  int hh = blockIdx.x & 7;    // head
  int lane = threadIdx.x;     // query token n
  size_t base = ((size_t)((bw << 3) + hh)) << 11;  // *(64*32)
  const float4* ksrc = (const float4*)(kb + base) + lane * 8;
  const float4* vsrc = (const float4*)(vb + base) + lane * 8;
  float4* kdst = (float4*)kls + lane * 8;
  float4* vdst = (float4*)vls + lane * 8;
#pragma unroll
  for (int c = 0; c < 8; ++c) { kdst[c] = ksrc[c]; vdst[c] = vsrc[c]; }
  __syncthreads();
  float qr[32];
  const float4* qsrc = (const float4*)(qb + base) + lane * 8;
#pragma unroll
  for (int c = 0; c < 8; ++c) {
    float4 t = qsrc[c];
    qr[c*4+0] = t.x; qr[c*4+1] = t.y; qr[c*4+2] = t.z; qr[c*4+3] = t.w;
  }
  int g = g0 + bw;
  int wi = g & 255, wr = wi >> 4, wc = wi & 15;
  int i1 = lane >> 3, j1 = lane & 7;
  bool edge = (wr == 15) || (wc == 15);
  int rid1 = regid3(wr * 8 + i1) * 3 + regid3(wc * 8 + j1);
  float S[64];
  float mx = -1e30f;
#pragma unroll
  for (int m = 0; m < 64; ++m) {
    const float4* kr = (const float4*)(kls + m * 32);
    float s = 0.f;
#pragma unroll
    for (int c = 0; c < 8; ++c) {
      float4 kv = kr[c];
      s += qr[c*4+0]*kv.x + qr[c*4+1]*kv.y + qr[c*4+2]*kv.z + qr[c*4+3]*kv.w;
    }
    int i2 = m >> 3, j2 = m & 7;
    int idx = (i1 - i2 + 7) * 15 + (j1 - j2 + 7);
    s += rpb[idx * 8 + hh];
    if (edge) {
      int rid2 = regid3(wr * 8 + i2) * 3 + regid3(wc * 8 + j2);
      if (rid2 != rid1) s -= 100.f;
    }
    S[m] = s;
    mx = fmaxf(mx, s);
  }
  float sum = 0.f;
#pragma unroll
  for (int m = 0; m < 64; ++m) { float p = expf(S[m] - mx); S[m] = p; sum += p; }
  float inv = 1.f / sum;
  float acc[32];
#pragma unroll
  for (int c = 0; c < 32; ++c) acc[c] = 0.f;
#pragma unroll
  for (int m = 0; m < 64; ++m) {
    float p = S[m];
    const float4* vr = (const float4*)(vls + m * 32);
#pragma unroll
    for (int c = 0; c < 8; ++c) {
      float4 vv = vr[c];
      acc[c*4+0] += p * vv.x; acc[c*4+1] += p * vv.y;
      acc[c*4+2] += p * vv.z; acc[c*4+3] += p * vv.w;
    }
  }
  float4* dst = (float4*)(ao + ((size_t)((bw << 6) + lane)) * 256 + hh * 32);
#pragma unroll
  for (int c = 0; c < 8; ++c)
    dst[c] = make_float4(acc[c*4+0]*inv, acc[c*4+1]*inv, acc[c*4+2]*inv, acc[c*4+3]*inv);
}

// ---------------- scatter (window order -> image order) + residual ----------------
__global__ __launch_bounds__(256)
void scatter_kernel(const float* __restrict__ x, const float* __restrict__ po,
                    float* __restrict__ out, int g0)
{
  int gid  = blockIdx.x * 4 + (threadIdx.x >> 6);
  int lane = threadIdx.x & 63;
  int g = g0 + (gid >> 6);
  int t = win_tok_to_t(g, gid & 63);
  float4 xv = ((const float4*)x)[(size_t)t * 64 + lane];
  float4 pv = ((const float4*)po)[(size_t)gid * 64 + lane];
  ((float4*)out)[(size_t)t * 64 + lane] =
      make_float4(xv.x + pv.x, xv.y + pv.y, xv.z + pv.z, xv.w + pv.w);
}

// ---------------- LN2 row stats (mean, rstd) ----------------
__global__ __launch_bounds__(256)
void stats_kernel(const float* __restrict__ x2, float2* __restrict__ stats)
{
  int t    = blockIdx.x * 4 + (threadIdx.x >> 6);
  int lane = threadIdx.x & 63;
  float4 v = ((const float4*)x2)[(size_t)t * 64 + lane];
  float s = v.x + v.y + v.z + v.w;
  float q = v.x * v.x + v.y * v.y + v.z * v.z + v.w * v.w;
#pragma unroll
  for (int m = 1; m < 64; m <<= 1) { s += __shfl_xor(s, m, 64); q += __shfl_xor(q, m, 64); }
  if (lane == 0) {
    float mean = s * 0.00390625f;
    float var  = q * 0.00390625f - mean * mean;
    stats[t] = make_float2(mean, rsqrtf(var + 1e-5f));
  }
}

// ---------------- launch ----------------
extern "C" void kernel_launch(void* const* d_in, const int* in_sizes, int n_in,
                              void* d_out, int out_size, void* d_ws, size_t ws_size,
                              hipStream_t stream)
{
  const float* x      = (const float*)d_in[0];
  const float* qkv_w  = (const float*)d_in[1];
  const float* qkv_b  = (const float*)d_in[2];
  const float* proj_w = (const float*)d_in[3];
  const float* proj_b = (const float*)d_in[4];
  const float* rpb    = (const float*)d_in[5];
  const float* g1     = (const float*)d_in[6];
  const float* b1     = (const float*)d_in[7];
  const float* g2     = (const float*)d_in[8];
  const float* b2     = (const float*)d_in[9];
  const float* fc1_w  = (const float*)d_in[10];
  const float* fc1_b  = (const float*)d_in[11];
  const float* fc2_w  = (const float*)d_in[12];
  const float* fc2_b  = (const float*)d_in[13];
  float* out = (float*)d_out;

  char* ws = (char*)d_ws;
  float2* stats = (float2*)ws;                 // 131072 * 8 B = 1 MB
  char* pb = ws + (1 << 20);
  size_t R = ws_size > (1 << 20) ? ws_size - (1 << 20) : 0;

  // windows per chunk: 6 * 64KB = 384KB per window of scratch
  int Gc = 2048;
  while (Gc > 2 && (size_t)Gc * 393216ULL > R) Gc >>= 1;

  float* ln1w = (float*)pb;                         // Gc*64*256
  float* qb = ln1w + (size_t)Gc * 16384;            // Gc*8*64*32
  float* kb = qb   + (size_t)Gc * 16384;
  float* vb = kb   + (size_t)Gc * 16384;
  float* ao = vb   + (size_t)Gc * 16384;            // Gc*64*256
  float* po = ao   + (size_t)Gc * 16384;            // Gc*64*256

  for (int g0 = 0; g0 < NWIN_TOTAL; g0 += Gc) {
    int nT = Gc * 64;
    ln1_kernel<<<nT / 4, 256, 0, stream>>>(x, g1, b1, ln1w, g0);

    GArgs qa = {}; qa.A = ln1w; qa.Bw = qkv_w; qa.bias = qkv_b;
    qa.o0 = qb; qa.o1 = kb; qa.o2 = vb; qa.M = nT; qa.N = 768; qa.K = 256;
    gemm_kernel<1><<<dim3(6, nT / 128), 256, 0, stream>>>(qa);

    attn_kernel<<<Gc * 8, 64, 0, stream>>>(qb, kb, vb, rpb, ao, g0);

    GArgs pa = {}; pa.A = ao; pa.Bw = proj_w; pa.bias = proj_b;
    pa.o0 = po; pa.M = nT; pa.N = 256; pa.K = 256;
    gemm_kernel<0><<<dim3(2, nT / 128), 256, 0, stream>>>(pa);

    scatter_kernel<<<nT / 4, 256, 0, stream>>>(x, po, out, g0);
  }

  stats_kernel<<<TOK_TOTAL / 4, 256, 0, stream>>>(out, stats);

  // MLP chunks: h1 needs Tc*1024*4 bytes
  int Tc = TOK_TOTAL;
  while (Tc > 128 && (size_t)Tc * 4096ULL > R) Tc >>= 1;
  float* h1 = (float*)pb;
  for (int t0 = 0; t0 < TOK_TOTAL; t0 += Tc) {
    GArgs fa = {}; fa.Bw = fc1_w; fa.bias = fc1_b; fa.o0 = h1;
    fa.M = Tc; fa.N = 1024; fa.K = 256;
    fa.xsrc = out + (size_t)t0 * 256; fa.stats = stats + t0;
    fa.gamma = g2; fa.beta = b2;
    gemm_kernel<2><<<dim3(8, Tc / 128), 256, 0, stream>>>(fa);

    GArgs fb = {}; fb.A = h1; fb.Bw = fc2_w; fb.bias = fc2_b;
    fb.o0 = out + (size_t)t0 * 256; fb.M = Tc; fb.N = 256; fb.K = 1024;
    fb.resid = out + (size_t)t0 * 256;
    gemm_kernel<3><<<dim3(2, Tc / 128), 256, 0, stream>>>(fb);
  }
}

// Round 2
// 1028.869 us; speedup vs baseline: 2.8571x; 2.8571x over previous
//
#include <hip/hip_runtime.h>
#include <math.h>

// Swin block: B=8 H=W=128 C=256 NH=8 HD=32 WS=8 SS=4, N=64 tokens/window,
// 2048 windows, 131072 tokens.

#define NWIN_TOTAL 2048
#define TOK_TOTAL  131072
#define SCALE_Q    0.17677669529663687f  // 32^-0.5

typedef unsigned short u16;
typedef __attribute__((ext_vector_type(4))) unsigned short u16x4;
typedef __attribute__((ext_vector_type(8))) unsigned short u16x8;
typedef __attribute__((ext_vector_type(8))) short bf16x8;   // MFMA A/B frag (4 VGPR)
typedef __attribute__((ext_vector_type(4))) float f32x4;    // MFMA C/D frag

#define AS1 __attribute__((address_space(1)))
#define AS3 __attribute__((address_space(3)))
#define GLOAD_LDS16(g, l) \
  __builtin_amdgcn_global_load_lds((const AS1 unsigned int*)(g), (AS3 unsigned int*)(l), 16, 0, 0)

__device__ __forceinline__ float bf2f(u16 u) {
  union { unsigned int i; float f; } c; c.i = ((unsigned int)u) << 16; return c.f;
}
__device__ __forceinline__ u16 f2bf(float f) {
  union { float f; unsigned int i; } c; c.f = f;
  return (u16)((c.i + 0x7fff + ((c.i >> 16) & 1)) >> 16);
}
__device__ __forceinline__ int regid3(int h) { return h < 120 ? 0 : (h < 124 ? 1 : 2); }
__device__ __forceinline__ float gelu_f(float v) {
  return 0.5f * v * (1.0f + erff(v * 0.7071067811865475f));
}

// (window g, token n) -> flat token index in image space (shift applied)
__device__ __forceinline__ int win_tok_to_t(int g, int n) {
  int b = g >> 8, wi = g & 255;
  int wr = wi >> 4, wc = wi & 15;
  int hs = wr * 8 + (n >> 3), ws2 = wc * 8 + (n & 7);
  int h = (hs + 4) & 127, w = (ws2 + 4) & 127;
  return (b << 14) + (h << 7) + w;
}

// ---------------- weight convert + transpose: [K][N] f32 -> [N][K] bf16 ----------------
__global__ __launch_bounds__(256)
void wconv_kernel(const float* __restrict__ w, u16* __restrict__ wt, int K, int N)
{
  int i = blockIdx.x * 256 + threadIdx.x;
  if (i >= K * N) return;
  int k = i / N, n = i - k * N;
  wt[(size_t)n * K + k] = f2bf(w[i]);
}

// ---------------- LN1 (gather into window order), bf16 out ----------------
__global__ __launch_bounds__(256)
void ln1_kernel(const float* __restrict__ x, const float* __restrict__ g1,
                const float* __restrict__ b1, u16* __restrict__ outw, int g0)
{
  int gid  = blockIdx.x * 4 + (threadIdx.x >> 6);
  int lane = threadIdx.x & 63;
  int g = g0 + (gid >> 6);
  int t = win_tok_to_t(g, gid & 63);
  float4 v = ((const float4*)x)[(size_t)t * 64 + lane];
  float s = v.x + v.y + v.z + v.w;
  float q = v.x * v.x + v.y * v.y + v.z * v.z + v.w * v.w;
#pragma unroll
  for (int m = 1; m < 64; m <<= 1) { s += __shfl_xor(s, m, 64); q += __shfl_xor(q, m, 64); }
  float mean = s * 0.00390625f;
  float var  = q * 0.00390625f - mean * mean;
  float rstd = rsqrtf(var + 1e-5f);
  float4 gg = ((const float4*)g1)[lane];
  float4 bb = ((const float4*)b1)[lane];
  u16x4 o;
  o.x = f2bf((v.x - mean) * rstd * gg.x + bb.x);
  o.y = f2bf((v.y - mean) * rstd * gg.y + bb.y);
  o.z = f2bf((v.z - mean) * rstd * gg.z + bb.z);
  o.w = f2bf((v.w - mean) * rstd * gg.w + bb.w);
  *(u16x4*)(outw + (size_t)gid * 256 + lane * 4) = o;
}

// ---------------- LN2, bf16 out ----------------
__global__ __launch_bounds__(256)
void ln2_kernel(const float* __restrict__ x2, const float* __restrict__ g2,
                const float* __restrict__ b2, u16* __restrict__ outw)
{
  int t    = blockIdx.x * 4 + (threadIdx.x >> 6);
  int lane = threadIdx.x & 63;
  float4 v = ((const float4*)x2)[(size_t)t * 64 + lane];
  float s = v.x + v.y + v.z + v.w;
  float q = v.x * v.x + v.y * v.y + v.z * v.z + v.w * v.w;
#pragma unroll
  for (int m = 1; m < 64; m <<= 1) { s += __shfl_xor(s, m, 64); q += __shfl_xor(q, m, 64); }
  float mean = s * 0.00390625f;
  float var  = q * 0.00390625f - mean * mean;
  float rstd = rsqrtf(var + 1e-5f);
  float4 gg = ((const float4*)g2)[lane];
  float4 bb = ((const float4*)b2)[lane];
  u16x4 o;
  o.x = f2bf((v.x - mean) * rstd * gg.x + bb.x);
  o.y = f2bf((v.y - mean) * rstd * gg.y + bb.y);
  o.z = f2bf((v.z - mean) * rstd * gg.z + bb.z);
  o.w = f2bf((v.w - mean) * rstd * gg.w + bb.w);
  *(u16x4*)(outw + (size_t)t * 256 + lane * 4) = o;
}

// ---------------- bf16 MFMA GEMM, 128x128 tile, BK=32, double-buffered LDS ----------------
// A: [M][K] bf16.  Bt: [N][K] bf16 (pre-transposed weight).
// MODE 0: +bias -> o (f32)                      (proj)
// MODE 1: +bias, q-scale, scatter q/k/v bf16    (qkv)
// MODE 2: +bias, GELU -> h (bf16)               (fc1)
// MODE 3: +bias +resid -> o (f32)               (fc2)
struct BArgs {
  const u16* A; const u16* Bt; const float* bias;
  float* o; u16* h; u16* q; u16* k; u16* v;
  const float* resid;
  int M, N, K;
};

template<int MODE>
__global__ __launch_bounds__(256)
void bgemm_kernel(BArgs a)
{
  __shared__ u16 As[2][4096];   // [buf][128 rows][32 k]
  __shared__ u16 Bs[2][4096];   // [buf][128 cols][32 k]
  const int tid  = threadIdx.x;
  const int wid  = tid >> 6, lane = tid & 63;
  const int wr   = wid >> 1, wc = wid & 1;
  const int rowBase = blockIdx.y * 128;
  const int colBase = blockIdx.x * 128;
  const int lr = lane >> 2;          // row within 16-row staging group
  const int lc = (lane & 3) * 8;     // k-element offset (16B granules)
  const int l15 = lane & 15, lhi = lane >> 4;

  f32x4 acc[4][4];
#pragma unroll
  for (int m = 0; m < 4; ++m)
#pragma unroll
    for (int n = 0; n < 4; ++n) acc[m][n] = (f32x4){0.f, 0.f, 0.f, 0.f};

  const int nkt = a.K >> 5;

#define STAGE(buf, kk)                                                          \
  {                                                                             \
    _Pragma("unroll")                                                           \
    for (int i = 0; i < 2; ++i) {                                               \
      const int srow = wid * 32 + i * 16;                                       \
      GLOAD_LDS16(a.A  + (size_t)(rowBase + srow + lr) * a.K + (kk) + lc,       \
                  &As[buf][srow * 32]);                                         \
      GLOAD_LDS16(a.Bt + (size_t)(colBase + srow + lr) * a.K + (kk) + lc,       \
                  &Bs[buf][srow * 32]);                                         \
    }                                                                           \
  }

  STAGE(0, 0);
  __syncthreads();
  int cur = 0;
  for (int kt = 0; kt < nkt; ++kt) {
    if (kt + 1 < nkt) STAGE(cur ^ 1, (kt + 1) << 5);
    bf16x8 af[4], bfr[4];
#pragma unroll
    for (int m = 0; m < 4; ++m)
      af[m] = *(const bf16x8*)&As[cur][(wr * 64 + m * 16 + l15) * 32 + lhi * 8];
#pragma unroll
    for (int n = 0; n < 4; ++n)
      bfr[n] = *(const bf16x8*)&Bs[cur][(wc * 64 + n * 16 + l15) * 32 + lhi * 8];
#pragma unroll
    for (int m = 0; m < 4; ++m)
#pragma unroll
      for (int n = 0; n < 4; ++n)
        acc[m][n] = __builtin_amdgcn_mfma_f32_16x16x32_bf16(af[m], bfr[n], acc[m][n], 0, 0, 0);
    __syncthreads();
    cur ^= 1;
  }
#undef STAGE

  // ---- epilogue: lane l, reg r holds D[row=(l>>4)*4+r][col=l&15] of each 16x16 frag ----
#pragma unroll
  for (int n = 0; n < 4; ++n) {
    const int col16 = colBase + wc * 64 + n * 16;
    const int col = col16 + l15;
    const float bv = a.bias[col];
    u16* qdst = nullptr; float scl = 1.f; size_t obase = 0;
    if (MODE == 1) {
      const int s = col16 >> 8, head = (col16 >> 5) & 7, hd = col16 & 31;
      qdst = (s == 0) ? a.q : (s == 1) ? a.k : a.v;
      if (s == 0) scl = SCALE_Q;
      obase = ((size_t)head << 11) + hd + l15;
    }
#pragma unroll
    for (int m = 0; m < 4; ++m) {
      const int row0 = rowBase + wr * 64 + m * 16 + lhi * 4;
#pragma unroll
      for (int r = 0; r < 4; ++r) {
        const int row = row0 + r;
        const float v = acc[m][n][r] + bv;
        if (MODE == 0) {
          a.o[(size_t)row * a.N + col] = v;
        } else if (MODE == 1) {
          const int gw = row >> 6, tok = row & 63;
          qdst[((size_t)gw << 14) + obase + ((size_t)tok << 5)] = f2bf(v * scl);
        } else if (MODE == 2) {
          a.h[(size_t)row * a.N + col] = f2bf(gelu_f(v));
        } else {
          a.o[(size_t)row * 256 + col] = v + a.resid[(size_t)row * 256 + col];
        }
      }
    }
  }
}

// ---------------- windowed attention: one wave per (window, head), bf16 in/out ----------------
__global__ __launch_bounds__(64)
void attn_kernel(const u16* __restrict__ qb, const u16* __restrict__ kb,
                 const u16* __restrict__ vb, const float* __restrict__ rpb,
                 u16* __restrict__ ao, int g0)
{
  __shared__ float kls[64 * 32];
  __shared__ float vls[64 * 32];
  int bw = blockIdx.x >> 3;
  int hh = blockIdx.x & 7;
  int lane = threadIdx.x;
  size_t base = ((size_t)((bw << 3) + hh)) << 11;
  const u16* ks = kb + base + lane * 32;
  const u16* vs = vb + base + lane * 32;
#pragma unroll
  for (int c = 0; c < 4; ++c) {
    u16x8 kv = *(const u16x8*)(ks + c * 8);
    u16x8 vv = *(const u16x8*)(vs + c * 8);
#pragma unroll
    for (int j = 0; j < 8; ++j) {
      kls[lane * 32 + c * 8 + j] = bf2f(kv[j]);
      vls[lane * 32 + c * 8 + j] = bf2f(vv[j]);
    }
  }
  __syncthreads();
  float qr[32];
  const u16* qs = qb + base + lane * 32;
#pragma unroll
  for (int c = 0; c < 4; ++c) {
    u16x8 qv = *(const u16x8*)(qs + c * 8);
#pragma unroll
    for (int j = 0; j < 8; ++j) qr[c * 8 + j] = bf2f(qv[j]);
  }
  int g = g0 + bw;
  int wi = g & 255, wrw = wi >> 4, wcw = wi & 15;
  int i1 = lane >> 3, j1 = lane & 7;
  bool edge = (wrw == 15) || (wcw == 15);
  int rid1 = regid3(wrw * 8 + i1) * 3 + regid3(wcw * 8 + j1);
  float S[64];
  float mx = -1e30f;
#pragma unroll
  for (int m = 0; m < 64; ++m) {
    const float4* kr = (const float4*)(kls + m * 32);
    float s = 0.f;
#pragma unroll
    for (int c = 0; c < 8; ++c) {
      float4 kv = kr[c];
      s += qr[c*4+0]*kv.x + qr[c*4+1]*kv.y + qr[c*4+2]*kv.z + qr[c*4+3]*kv.w;
    }
    int i2 = m >> 3, j2 = m & 7;
    int idx = (i1 - i2 + 7) * 15 + (j1 - j2 + 7);
    s += rpb[idx * 8 + hh];
    if (edge) {
      int rid2 = regid3(wrw * 8 + i2) * 3 + regid3(wcw * 8 + j2);
      if (rid2 != rid1) s -= 100.f;
    }
    S[m] = s;
    mx = fmaxf(mx, s);
  }
  float sum = 0.f;
#pragma unroll
  for (int m = 0; m < 64; ++m) { float p = expf(S[m] - mx); S[m] = p; sum += p; }
  float inv = 1.f / sum;
  float acc[32];
#pragma unroll
  for (int c = 0; c < 32; ++c) acc[c] = 0.f;
#pragma unroll
  for (int m = 0; m < 64; ++m) {
    float p = S[m];
    const float4* vr = (const float4*)(vls + m * 32);
#pragma unroll
    for (int c = 0; c < 8; ++c) {
      float4 vv = vr[c];
      acc[c*4+0] += p * vv.x; acc[c*4+1] += p * vv.y;
      acc[c*4+2] += p * vv.z; acc[c*4+3] += p * vv.w;
    }
  }
  u16* dst = ao + ((size_t)((bw << 6) + lane)) * 256 + hh * 32;
#pragma unroll
  for (int c = 0; c < 4; ++c) {
    u16x8 o8;
#pragma unroll
    for (int j = 0; j < 8; ++j) o8[j] = f2bf(acc[c * 8 + j] * inv);
    *(u16x8*)(dst + c * 8) = o8;
  }
}

// ---------------- scatter (window order -> image order) + residual ----------------
__global__ __launch_bounds__(256)
void scatter_kernel(const float* __restrict__ x, const float* __restrict__ po,
                    float* __restrict__ out, int g0)
{
  int gid  = blockIdx.x * 4 + (threadIdx.x >> 6);
  int lane = threadIdx.x & 63;
  int g = g0 + (gid >> 6);
  int t = win_tok_to_t(g, gid & 63);
  float4 xv = ((const float4*)x)[(size_t)t * 64 + lane];
  float4 pv = ((const float4*)po)[(size_t)gid * 64 + lane];
  ((float4*)out)[(size_t)t * 64 + lane] =
      make_float4(xv.x + pv.x, xv.y + pv.y, xv.z + pv.z, xv.w + pv.w);
}

// ---------------- launch ----------------
extern "C" void kernel_launch(void* const* d_in, const int* in_sizes, int n_in,
                              void* d_out, int out_size, void* d_ws, size_t ws_size,
                              hipStream_t stream)
{
  const float* x      = (const float*)d_in[0];
  const float* qkv_w  = (const float*)d_in[1];
  const float* qkv_b  = (const float*)d_in[2];
  const float* proj_w = (const float*)d_in[3];
  const float* proj_b = (const float*)d_in[4];
  const float* rpb    = (const float*)d_in[5];
  const float* g1     = (const float*)d_in[6];
  const float* b1     = (const float*)d_in[7];
  const float* g2     = (const float*)d_in[8];
  const float* b2     = (const float*)d_in[9];
  const float* fc1_w  = (const float*)d_in[10];
  const float* fc1_b  = (const float*)d_in[11];
  const float* fc2_w  = (const float*)d_in[12];
  const float* fc2_b  = (const float*)d_in[13];
  float* out = (float*)d_out;
  char* ws = (char*)d_ws;

  // bf16 transposed weights
  u16* qkvT  = (u16*)ws;            // [768][256]
  u16* projT = qkvT + 196608;       // [256][256]
  u16* fc1T  = projT + 65536;       // [1024][256]
  u16* fc2T  = fc1T + 262144;       // [256][1024]
  u16* ln2w  = fc2T + 262144;       // [131072][256] bf16 = 64 MB
  char* pb = (char*)(ln2w + 33554432);
  size_t used = 1572864ULL + 67108864ULL;
  size_t R = ws_size > used ? ws_size - used : 0;

  wconv_kernel<<<(196608 + 255) / 256, 256, 0, stream>>>(qkv_w, qkvT, 256, 768);
  wconv_kernel<<<(65536  + 255) / 256, 256, 0, stream>>>(proj_w, projT, 256, 256);
  wconv_kernel<<<(262144 + 255) / 256, 256, 0, stream>>>(fc1_w, fc1T, 256, 1024);
  wconv_kernel<<<(262144 + 255) / 256, 256, 0, stream>>>(fc2_w, fc2T, 1024, 256);

  // attention-phase scratch per window: ln1w 32K + q/k/v 3*32K + ao 32K + po 64K = 224K
  int Gc = 2048;
  while (Gc > 2 && (size_t)Gc * 229376ULL > R) Gc >>= 1;

  u16* ln1w = (u16*)pb;
  u16* qb = ln1w + (size_t)Gc * 16384;
  u16* kb = qb + (size_t)Gc * 16384;
  u16* vb = kb + (size_t)Gc * 16384;
  u16* ao = vb + (size_t)Gc * 16384;
  float* po = (float*)(ao + (size_t)Gc * 16384);

  for (int g0 = 0; g0 < NWIN_TOTAL; g0 += Gc) {
    int nT = Gc * 64;
    ln1_kernel<<<nT / 4, 256, 0, stream>>>(x, g1, b1, ln1w, g0);

    BArgs qa = {}; qa.A = ln1w; qa.Bt = qkvT; qa.bias = qkv_b;
    qa.q = qb; qa.k = kb; qa.v = vb; qa.M = nT; qa.N = 768; qa.K = 256;
    bgemm_kernel<1><<<dim3(6, nT / 128), 256, 0, stream>>>(qa);

    attn_kernel<<<Gc * 8, 64, 0, stream>>>(qb, kb, vb, rpb, ao, g0);

    BArgs pa = {}; pa.A = ao; pa.Bt = projT; pa.bias = proj_b;
    pa.o = po; pa.M = nT; pa.N = 256; pa.K = 256;
    bgemm_kernel<0><<<dim3(2, nT / 128), 256, 0, stream>>>(pa);

    scatter_kernel<<<nT / 4, 256, 0, stream>>>(x, po, out, g0);
  }

  ln2_kernel<<<TOK_TOTAL / 4, 256, 0, stream>>>(out, g2, b2, ln2w);

  // MLP scratch: h1 = Tc*1024 bf16 = Tc*2048 B
  int Tc = TOK_TOTAL;
  while (Tc > 128 && (size_t)Tc * 2048ULL > R) Tc >>= 1;
  u16* h1 = (u16*)pb;
  for (int t0 = 0; t0 < TOK_TOTAL; t0 += Tc) {
    BArgs fa = {}; fa.A = ln2w + (size_t)t0 * 256; fa.Bt = fc1T; fa.bias = fc1_b;
    fa.h = h1; fa.M = Tc; fa.N = 1024; fa.K = 256;
    bgemm_kernel<2><<<dim3(8, Tc / 128), 256, 0, stream>>>(fa);

    BArgs fb = {}; fb.A = h1; fb.Bt = fc2T; fb.bias = fc2_b;
    fb.o = out + (size_t)t0 * 256; fb.resid = out + (size_t)t0 * 256;
    fb.M = Tc; fb.N = 256; fb.K = 1024;
    bgemm_kernel<3><<<dim3(2, Tc / 128), 256, 0, stream>>>(fb);
  }
}